// Round 3
// baseline (549.751 us; speedup 1.0000x reference)
//
#include <hip/hip_runtime.h>
#include <math.h>

#define DD   256
#define HHH  96
#define WWW  96
#define NB   8
#define LL   9216            // HHH*WWW
#define NPIX (NB*LL)         // 73728
#define TCH  32              // scan chunk length
#define NCH  (LL/TCH)        // 288
#define NSTRIPE 576          // NPIX/128 M-tiles
#define GXB  128             // blocks per col-group (persistent stride)

typedef __bf16 bf16_8 __attribute__((ext_vector_type(8)));
typedef float  f32_4  __attribute__((ext_vector_type(4)));

static __device__ __forceinline__ float sigmoidf_(float x) {
    return 1.0f / (1.0f + expf(-x));
}

// async global->LDS, 16B per lane. Dest must be wave-uniform base (+lane*16 by HW).
typedef const __attribute__((address_space(1))) void gas_void;
typedef __attribute__((address_space(3))) void las_void;
static __device__ __forceinline__ void glld16(const void* g, void* l) {
    __builtin_amdgcn_global_load_lds((gas_void*)g, (las_void*)l, 16, 0, 0);
}

template<int DIR>
static __device__ __forceinline__ int spidx(int t) {
    if (DIR == 0) return t;
    int w = t / HHH;
    int h = t - w * HHH;
    return h * WWW + w;
}

// ---------------- weight transpose + bf16 cast ----------------
__global__ __launch_bounds__(256) void wcvt_kernel(const float* __restrict__ w_in,
                                                   const float* __restrict__ w_out,
                                                   __bf16* __restrict__ w_inT,
                                                   __bf16* __restrict__ w_outT) {
    int i = blockIdx.x * 256 + threadIdx.x;
    int n = i >> 8, k = i & 255;
    w_inT[i] = (__bf16)w_in[k * 512 + n];
    if (i < 256 * 256) w_outT[i] = (__bf16)w_out[k * 256 + n];
}

// ---------------- LayerNorm over channels -> bf16 ----------------
__global__ __launch_bounds__(256) void ln_kernel(const float* __restrict__ x,
                                                 const float* __restrict__ g,
                                                 const float* __restrict__ b,
                                                 __bf16* __restrict__ h) {
    int wv = threadIdx.x >> 6, lane = threadIdx.x & 63;
    int pix = blockIdx.x * 4 + wv;
    const float4 v = *(const float4*)&x[(size_t)pix * DD + lane * 4];
    float s  = v.x + v.y + v.z + v.w;
    float s2 = v.x * v.x + v.y * v.y + v.z * v.z + v.w * v.w;
    #pragma unroll
    for (int o = 32; o > 0; o >>= 1) {
        s  += __shfl_xor(s, o, 64);
        s2 += __shfl_xor(s2, o, 64);
    }
    float mu  = s * (1.0f / 256.0f);
    float var = s2 * (1.0f / 256.0f) - mu * mu;
    float r = rsqrtf(var + 1e-5f);
    float4 gg = *(const float4*)&g[lane * 4];
    float4 bb = *(const float4*)&b[lane * 4];
    union { ushort4 u; __bf16 e[4]; } o4;
    o4.e[0] = (__bf16)((v.x - mu) * r * gg.x + bb.x);
    o4.e[1] = (__bf16)((v.y - mu) * r * gg.y + bb.y);
    o4.e[2] = (__bf16)((v.z - mu) * r * gg.z + bb.z);
    o4.e[3] = (__bf16)((v.w - mu) * r * gg.w + bb.w);
    *(ushort4*)&h[(size_t)pix * DD + lane * 4] = o4.u;
}

// ---------------- bf16 MFMA GEMM: B-stationary, barrier-free streaming ------
// B (128 cols x K=256, 64KB) staged in LDS once via glld16; ONE barrier.
// A streamed global->VGPR as MFMA fragments; persistent M-stripe loop with
// register double-buffering (K-halves). bias folded into MFMA C-init.
// MODE 0: col-group 0/1 -> x_in (bf16); group 2/3 -> sigmoid -> gate (bf16)
// MODE 1: out_f32 = acc(+bias) + x0
template<int MODE>
__global__ __launch_bounds__(256, 2) void gemm_bf16(const __bf16* __restrict__ A,
                                                 const __bf16* __restrict__ BT,
                                                 const float* __restrict__ bias,
                                                 __bf16* __restrict__ out_xin,
                                                 __bf16* __restrict__ out_gate,
                                                 float* __restrict__ out_f32,
                                                 const float* __restrict__ x0) {
    const int K = 256;
    __shared__ __bf16 Bs[8][128 * 32];   // 64 KB: [k-chunk][col-row][32 k]
    int tid = threadIdx.x;
    int lane = tid & 63, wv = tid >> 6;
    int colBase = blockIdx.y * 128;

    // ---- stage B once ----
    int srow = tid >> 2, sseg = tid & 3;
    const __bf16* bS0 = BT + (size_t)(colBase + srow) * K + sseg * 8;
    const __bf16* bS1 = bS0 + (size_t)64 * K;
    int wvoff = wv * 1024;
    #pragma unroll
    for (int t = 0; t < 8; ++t) {
        glld16(bS0 + t * 32, (char*)&Bs[t][0] + wvoff);
        glld16(bS1 + t * 32, (char*)&Bs[t][0] + 4096 + wvoff);
    }

    int m0 = (wv >> 1) * 64, n0 = (wv & 1) * 64;
    int fr = lane & 15, fq = lane >> 4;

    float bv[4];
    #pragma unroll
    for (int ni = 0; ni < 4; ni++)
        bv[ni] = bias[colBase + n0 + ni * 16 + fr];

    // A fragment lane base: row (m0+fr), k-seg fq*8
    const __bf16* Abase = A + (size_t)(m0 + fr) * K + fq * 8;

    bf16_8 aP[4][4], aQ[4][4];   // K-half buffers (half = 4 k-chunks of 32)
#define LDA(dst, stripe, half)                                                 \
    do {                                                                       \
        const __bf16* p_ = Abase + (size_t)(stripe) * 128 * K + (half) * 128;  \
        _Pragma("unroll")                                                      \
        for (int mi_ = 0; mi_ < 4; mi_++)                                      \
            _Pragma("unroll")                                                  \
            for (int kk_ = 0; kk_ < 4; kk_++)                                  \
                dst[mi_][kk_] = *(const bf16_8*)(p_ + (size_t)mi_ * 16 * K     \
                                                 + kk_ * 32);                  \
    } while (0)

    int s = blockIdx.x;
    LDA(aP, s, 0);
    LDA(aQ, s, 1);
    __syncthreads();                     // B (and prologue A) ready

    while (s < NSTRIPE) {
        int sn = s + GXB;
        bool more = (sn < NSTRIPE);

        f32_4 acc[4][4];
        #pragma unroll
        for (int mi = 0; mi < 4; mi++)
            #pragma unroll
            for (int ni = 0; ni < 4; ni++)
                acc[mi][ni] = (f32_4){bv[ni], bv[ni], bv[ni], bv[ni]};

        // half 0: k-chunks 0..3 from aP
        #pragma unroll
        for (int kk = 0; kk < 4; kk++) {
            bf16_8 bb[4];
            #pragma unroll
            for (int ni = 0; ni < 4; ni++)
                bb[ni] = *(const bf16_8*)&Bs[kk][(n0 + ni * 16 + fr) * 32 + fq * 8];
            #pragma unroll
            for (int mi = 0; mi < 4; mi++)
                #pragma unroll
                for (int ni = 0; ni < 4; ni++)
                    acc[mi][ni] = __builtin_amdgcn_mfma_f32_16x16x32_bf16(
                        aP[mi][kk], bb[ni], acc[mi][ni], 0, 0, 0);
        }
        if (more) LDA(aP, sn, 0);        // prefetch next stripe, half 0

        // half 1: k-chunks 4..7 from aQ
        #pragma unroll
        for (int kk = 0; kk < 4; kk++) {
            bf16_8 bb[4];
            #pragma unroll
            for (int ni = 0; ni < 4; ni++)
                bb[ni] = *(const bf16_8*)&Bs[kk + 4][(n0 + ni * 16 + fr) * 32 + fq * 8];
            #pragma unroll
            for (int mi = 0; mi < 4; mi++)
                #pragma unroll
                for (int ni = 0; ni < 4; ni++)
                    acc[mi][ni] = __builtin_amdgcn_mfma_f32_16x16x32_bf16(
                        aQ[mi][kk], bb[ni], acc[mi][ni], 0, 0, 0);
        }
        if (more) LDA(aQ, sn, 1);        // prefetch next stripe, half 1

        // epilogue for stripe s (no barriers; overlaps with prefetch)
        int rowW = s * 128 + m0 + fq * 4;
        if (MODE == 0) {
            bool gateBlk = (colBase >= 256);
            __bf16* outp = gateBlk ? out_gate : out_xin;
            int colO = colBase + n0 + fr - (gateBlk ? 256 : 0);
            #pragma unroll
            for (int mi = 0; mi < 4; mi++)
                #pragma unroll
                for (int ni = 0; ni < 4; ni++)
                    #pragma unroll
                    for (int r = 0; r < 4; r++) {
                        float v = acc[mi][ni][r];
                        if (gateBlk) v = sigmoidf_(v);
                        outp[(size_t)(rowW + mi * 16 + r) * 256 + colO + ni * 16]
                            = (__bf16)v;
                    }
        } else {
            int colW = colBase + n0 + fr;
            #pragma unroll
            for (int mi = 0; mi < 4; mi++)
                #pragma unroll
                for (int ni = 0; ni < 4; ni++)
                    #pragma unroll
                    for (int r = 0; r < 4; r++) {
                        size_t idx = (size_t)(rowW + mi * 16 + r) * 256
                                     + colW + ni * 16;
                        out_f32[idx] = acc[mi][ni][r] + x0[idx];
                    }
        }
        s = sn;
    }
#undef LDA
}

// ---------------- fused depthwise 3x3 conv + SiLU + row-scan chunk totals ----
static __device__ __forceinline__ void loadcol(const __bf16* __restrict__ xin,
                                               int b, int h, int w, int d,
                                               float c[3]) {
    if (w < 0 || w >= WWW) { c[0] = c[1] = c[2] = 0.f; return; }
    size_t base = ((size_t)b * LL + (size_t)h * WWW + w) * DD + d;
    c[0] = (h > 0)       ? (float)xin[base - (size_t)WWW * DD] : 0.f;
    c[1] = (float)xin[base];
    c[2] = (h + 1 < HHH) ? (float)xin[base + (size_t)WWW * DD] : 0.f;
}

__global__ __launch_bounds__(256) void conv_tot_kernel(const __bf16* __restrict__ xin,
                                                       const float* __restrict__ cw,
                                                       const float* __restrict__ cb,
                                                       const float* __restrict__ a_logit,
                                                       const float* __restrict__ ssm_b,
                                                       __bf16* __restrict__ u,
                                                       float* __restrict__ tot_f,
                                                       float* __restrict__ tot_b) {
    int cx = blockIdx.x, h = blockIdx.y, b = blockIdx.z;
    int d = threadIdx.x;
    int w0 = cx * TCH;
    float k[9];
    #pragma unroll
    for (int i = 0; i < 9; i++) k[i] = cw[i * DD + d];
    float bias = cb[d];
    float a = sigmoidf_(a_logit[d]);
    a = fminf(fmaxf(a, 1e-4f), 1.0f - 1e-4f);
    float bb = ssm_b[d];

    float cl[3], cc[3], cr[3];
    loadcol(xin, b, h, w0 - 1, d, cl);
    loadcol(xin, b, h, w0,     d, cc);
    loadcol(xin, b, h, w0 + 1, d, cr);

    float v[TCH];
    float sf = 0.f;
    size_t outBase = ((size_t)b * LL + (size_t)h * WWW + w0) * DD + d;
    #pragma unroll
    for (int j = 0; j < TCH; j++) {
        float nx[3];
        loadcol(xin, b, h, w0 + j + 2, d, nx);   // prefetch next column
        float acc = bias;
        acc += k[0] * cl[0] + k[1] * cc[0] + k[2] * cr[0];
        acc += k[3] * cl[1] + k[4] * cc[1] + k[5] * cr[1];
        acc += k[6] * cl[2] + k[7] * cc[2] + k[8] * cr[2];
        float uv = acc * sigmoidf_(acc);
        v[j] = uv;
        u[outBase + (size_t)j * DD] = (__bf16)uv;
        sf = a * sf + bb * uv;
        cl[0] = cc[0]; cl[1] = cc[1]; cl[2] = cc[2];
        cc[0] = cr[0]; cc[1] = cr[1]; cc[2] = cr[2];
        cr[0] = nx[0]; cr[1] = nx[1]; cr[2] = nx[2];
    }
    int chunk = h * 3 + cx;                       // row-major chunk id
    tot_f[((size_t)b * NCH + chunk) * DD + d] = sf;
    float sb = 0.f;
    #pragma unroll
    for (int j = TCH - 1; j >= 0; j--) sb = a * sb + bb * v[j];
    tot_b[((size_t)b * NCH + chunk) * DD + d] = sb;
}

// ---------------- scan pass A (col direction only now) ----------------
__global__ __launch_bounds__(256) void scan_totals_col(const __bf16* __restrict__ u,
                                                       const float* __restrict__ a_logit,
                                                       const float* __restrict__ ssm_b,
                                                       float* __restrict__ tot_f,
                                                       float* __restrict__ tot_b) {
    int blk = blockIdx.x;
    int b = blk / NCH, c = blk - b * NCH;
    int d = threadIdx.x;
    float a = sigmoidf_(a_logit[d]);
    a = fminf(fmaxf(a, 1e-4f), 1.0f - 1e-4f);
    float bb = ssm_b[d];
    size_t base = (size_t)b * LL * DD;
    int t0 = c * TCH;
    float v[TCH];
    #pragma unroll
    for (int j = 0; j < TCH; j++)
        v[j] = (float)u[base + (size_t)spidx<1>(t0 + j) * DD + d];
    float s = 0.f;
    #pragma unroll
    for (int j = 0; j < TCH; j++) s = a * s + bb * v[j];
    tot_f[(size_t)blk * DD + d] = s;
    s = 0.f;
    #pragma unroll
    for (int j = TCH - 1; j >= 0; j--) s = a * s + bb * v[j];
    tot_b[(size_t)blk * DD + d] = s;
}

// ---------------- scan pass B: all 4 carry scans in one dispatch -----------
__global__ __launch_bounds__(256) void scan_carries(const float* __restrict__ tot_all,
                                                    const float* __restrict__ a_logit,
                                                    float* __restrict__ car_all) {
    int b = blockIdx.x;
    int var = blockIdx.y;
    int d = threadIdx.x;
    float a = sigmoidf_(a_logit[d]);
    a = fminf(fmaxf(a, 1e-4f), 1.0f - 1e-4f);
    float a2 = a * a, a4 = a2 * a2, a8 = a4 * a4, a16 = a8 * a8;
    float q = a16 * a16;    // a^TCH
    const float* tot = tot_all + (size_t)var * NB * NCH * DD + (size_t)b * NCH * DD + d;
    float* car = car_all + (size_t)var * NB * NCH * DD + (size_t)b * NCH * DD + d;
    float P = 0.f;
    if ((var & 1) == 0) {
        for (int c0 = 0; c0 < NCH; c0 += 8) {
            float t[8];
            #pragma unroll
            for (int j = 0; j < 8; j++) t[j] = tot[(size_t)(c0 + j) * DD];
            #pragma unroll
            for (int j = 0; j < 8; j++) {
                car[(size_t)(c0 + j) * DD] = P;
                P = q * P + t[j];
            }
        }
    } else {
        for (int c0 = NCH - 8; c0 >= 0; c0 -= 8) {
            float t[8];
            #pragma unroll
            for (int j = 0; j < 8; j++) t[j] = tot[(size_t)(c0 + j) * DD];
            #pragma unroll
            for (int j = 7; j >= 0; j--) {
                car[(size_t)(c0 + j) * DD] = P;
                P = q * P + t[j];
            }
        }
    }
}

// ---------------- scan pass C: apply carries, emit 0.25*(yf+yb) ----------------
template<int DIR>
__global__ __launch_bounds__(256) void scan_apply(const __bf16* __restrict__ u,
                                                  const float* __restrict__ a_logit,
                                                  const float* __restrict__ ssm_b,
                                                  const float* __restrict__ ssm_c,
                                                  const float* __restrict__ ssm_d,
                                                  const float* __restrict__ car_f,
                                                  const float* __restrict__ car_b,
                                                  float* __restrict__ y,
                                                  const __bf16* __restrict__ gate,
                                                  __bf16* __restrict__ g) {
    int blk = blockIdx.x;
    int b = blk / NCH, c = blk - b * NCH;
    int d = threadIdx.x;
    float a = sigmoidf_(a_logit[d]);
    a = fminf(fmaxf(a, 1e-4f), 1.0f - 1e-4f);
    float bb = ssm_b[d], cc = ssm_c[d], dd = ssm_d[d];
    size_t base = (size_t)b * LL * DD;
    int t0 = c * TCH;
    float v[TCH];
    #pragma unroll
    for (int j = 0; j < TCH; j++)
        v[j] = (float)u[base + (size_t)spidx<DIR>(t0 + j) * DD + d];
    float yf[TCH];
    float s = car_f[(size_t)blk * DD + d];
    #pragma unroll
    for (int j = 0; j < TCH; j++) {
        s = a * s + bb * v[j];
        yf[j] = cc * s + dd * v[j];
    }
    s = car_b[(size_t)blk * DD + d];
    #pragma unroll
    for (int j = TCH - 1; j >= 0; j--) {
        s = a * s + bb * v[j];
        float val = 0.25f * (yf[j] + cc * s + dd * v[j]);
        size_t idx = base + (size_t)spidx<DIR>(t0 + j) * DD + d;
        if (DIR == 0) {
            y[idx] = val;
        } else {
            float t = y[idx] + val;
            g[idx] = (__bf16)(t * (float)gate[idx]);
        }
    }
}

extern "C" void kernel_launch(void* const* d_in, const int* in_sizes, int n_in,
                              void* d_out, int out_size, void* d_ws, size_t ws_size,
                              hipStream_t stream) {
    const float* x       = (const float*)d_in[0];
    const float* ln_g    = (const float*)d_in[1];
    const float* ln_b    = (const float*)d_in[2];
    const float* w_in    = (const float*)d_in[3];
    const float* b_in    = (const float*)d_in[4];
    const float* conv_w  = (const float*)d_in[5];
    const float* conv_b  = (const float*)d_in[6];
    const float* a_logit = (const float*)d_in[7];
    const float* ssm_b   = (const float*)d_in[8];
    const float* ssm_c   = (const float*)d_in[9];
    const float* ssm_d   = (const float*)d_in[10];
    const float* w_out   = (const float*)d_in[11];
    const float* b_out   = (const float*)d_in[12];
    float* out = (float*)d_out;

    char* ws = (char*)d_ws;
    const size_t SZH = (size_t)NPIX * DD * sizeof(__bf16);    // 37.7 MB
    const size_t TS  = (size_t)NB * NCH * DD * sizeof(float); // 2.36 MB

    __bf16* hB     = (__bf16*)(ws);                  // h, later reused as g
    __bf16* xinB   = (__bf16*)(ws + SZH);            // x_in bf16
    __bf16* uB     = (__bf16*)(ws + 2 * SZH);        // conv output bf16
    __bf16* gateB  = (__bf16*)(ws + 3 * SZH);        // gate bf16
    float*  tot    = (float*)(ws + 4 * SZH);         // [4][NB][NCH][DD]
    float*  car    = (float*)(ws + 4 * SZH + 4 * TS);
    __bf16* w_inT  = (__bf16*)(ws + 4 * SZH + 8 * TS);
    __bf16* w_outT = w_inT + 512 * 256;
    float* y = out;

    wcvt_kernel<<<512, 256, 0, stream>>>(w_in, w_out, w_inT, w_outT);
    ln_kernel<<<NPIX / 4, 256, 0, stream>>>(x, ln_g, ln_b, hB);
    gemm_bf16<0><<<dim3(GXB, 4), 256, 0, stream>>>(hB, w_inT, b_in,
                                                   xinB, gateB, nullptr, nullptr);
    // fused conv + row totals
    conv_tot_kernel<<<dim3(WWW / TCH, HHH, NB), 256, 0, stream>>>(
        xinB, conv_w, conv_b, a_logit, ssm_b, uB,
        tot + 0 * (size_t)NB * NCH * DD, tot + 1 * (size_t)NB * NCH * DD);
    // col totals
    scan_totals_col<<<NB * NCH, 256, 0, stream>>>(
        uB, a_logit, ssm_b,
        tot + 2 * (size_t)NB * NCH * DD, tot + 3 * (size_t)NB * NCH * DD);
    // all 4 carry scans
    scan_carries<<<dim3(NB, 4), 256, 0, stream>>>(tot, a_logit, car);
    // row apply -> y (fp32, d_out)
    scan_apply<0><<<NB * NCH, 256, 0, stream>>>(
        uB, a_logit, ssm_b, ssm_c, ssm_d,
        car + 0 * (size_t)NB * NCH * DD, car + 1 * (size_t)NB * NCH * DD,
        y, nullptr, nullptr);
    // col apply + gate -> g (bf16, reuses h slot)
    scan_apply<1><<<NB * NCH, 256, 0, stream>>>(
        uB, a_logit, ssm_b, ssm_c, ssm_d,
        car + 2 * (size_t)NB * NCH * DD, car + 3 * (size_t)NB * NCH * DD,
        y, gateB, hB);
    // out = x0 + g @ w_out + b_out
    gemm_bf16<1><<<dim3(GXB, 2), 256, 0, stream>>>(hB, w_outT, b_out,
                                                   nullptr, nullptr, out, x);
}

// Round 4
// 379.761 us; speedup vs baseline: 1.4476x; 1.4476x over previous
//
#include <hip/hip_runtime.h>
#include <math.h>

#define DD   256
#define HHH  96
#define WWW  96
#define NB   8
#define LL   9216            // HHH*WWW
#define NPIX (NB*LL)         // 73728
#define TCH  32              // scan chunk length
#define NCH  (LL/TCH)        // 288

typedef __bf16 bf16_8 __attribute__((ext_vector_type(8)));
typedef float  f32_4  __attribute__((ext_vector_type(4)));

static __device__ __forceinline__ float sigmoidf_(float x) {
    return 1.0f / (1.0f + expf(-x));
}

// async global->LDS, 16B per lane. Dest must be wave-uniform base (+lane*16 by HW).
typedef const __attribute__((address_space(1))) void gas_void;
typedef __attribute__((address_space(3))) void las_void;
static __device__ __forceinline__ void glld16(const void* g, void* l) {
    __builtin_amdgcn_global_load_lds((gas_void*)g, (las_void*)l, 16, 0, 0);
}

template<int DIR>
static __device__ __forceinline__ int spidx(int t) {
    if (DIR == 0) return t;
    int w = t / HHH;
    int h = t - w * HHH;
    return h * WWW + w;
}

// ---------------- weight transpose + bf16 cast ----------------
__global__ __launch_bounds__(256) void wcvt_kernel(const float* __restrict__ w_in,
                                                   const float* __restrict__ w_out,
                                                   __bf16* __restrict__ w_inT,
                                                   __bf16* __restrict__ w_outT) {
    int i = blockIdx.x * 256 + threadIdx.x;
    int n = i >> 8, k = i & 255;
    w_inT[i] = (__bf16)w_in[k * 512 + n];
    if (i < 256 * 256) w_outT[i] = (__bf16)w_out[k * 256 + n];
}

// ---------------- LayerNorm over channels -> bf16 ----------------
__global__ __launch_bounds__(256) void ln_kernel(const float* __restrict__ x,
                                                 const float* __restrict__ g,
                                                 const float* __restrict__ b,
                                                 __bf16* __restrict__ h) {
    int wv = threadIdx.x >> 6, lane = threadIdx.x & 63;
    int pix = blockIdx.x * 4 + wv;
    const float4 v = *(const float4*)&x[(size_t)pix * DD + lane * 4];
    float s  = v.x + v.y + v.z + v.w;
    float s2 = v.x * v.x + v.y * v.y + v.z * v.z + v.w * v.w;
    #pragma unroll
    for (int o = 32; o > 0; o >>= 1) {
        s  += __shfl_xor(s, o, 64);
        s2 += __shfl_xor(s2, o, 64);
    }
    float mu  = s * (1.0f / 256.0f);
    float var = s2 * (1.0f / 256.0f) - mu * mu;
    float r = rsqrtf(var + 1e-5f);
    float4 gg = *(const float4*)&g[lane * 4];
    float4 bb = *(const float4*)&b[lane * 4];
    union { ushort4 u; __bf16 e[4]; } o4;
    o4.e[0] = (__bf16)((v.x - mu) * r * gg.x + bb.x);
    o4.e[1] = (__bf16)((v.y - mu) * r * gg.y + bb.y);
    o4.e[2] = (__bf16)((v.z - mu) * r * gg.z + bb.z);
    o4.e[3] = (__bf16)((v.w - mu) * r * gg.w + bb.w);
    *(ushort4*)&h[(size_t)pix * DD + lane * 4] = o4.u;
}

// ---------------- bf16 MFMA GEMM (2-phase dbuf + glld16 + LDS epilogue) ----
// K-loop identical to R1 (best-known). Epilogue: acc -> LDS (padded) ->
// coalesced 16B/lane streaming stores (and x0 float4 add for MODE 1).
// MODE 0 (N=512): cols<256 -> x_in (bf16); cols>=256 -> sigmoid -> gate (bf16)
// MODE 1 (N=256): out_f32 = acc + bias + x0
template<int MODE>
__global__ __launch_bounds__(256) void gemm_bf16(const __bf16* __restrict__ A,
                                                 const __bf16* __restrict__ BT,
                                                 const float* __restrict__ bias,
                                                 __bf16* __restrict__ out_xin,
                                                 __bf16* __restrict__ out_gate,
                                                 float* __restrict__ out_f32,
                                                 const float* __restrict__ x0) {
    const int K = 256;
    const int BK = 32;
    __shared__ __align__(16) char SM[32768];
    auto As = (__bf16 (*)[128 * BK])SM;            // As[0], As[1] (8KB each)
    auto Bs = (__bf16 (*)[128 * BK])(SM + 16384);  // Bs[0], Bs[1]
    int tid = threadIdx.x;
    int lane = tid & 63, wv = tid >> 6;
    int rowBase = blockIdx.x * 128;
    int colBase = blockIdx.y * 128;

    // staging: thread covers 16B chunk c=tid; chunk c -> row=c>>2, seg=c&3
    int srow = tid >> 2, sseg = tid & 3;
    const __bf16* aS0 = A  + (size_t)(rowBase + srow) * K + sseg * 8;
    const __bf16* aS1 = A  + (size_t)(rowBase + srow + 64) * K + sseg * 8;
    const __bf16* bS0 = BT + (size_t)(colBase + srow) * K + sseg * 8;
    const __bf16* bS1 = BT + (size_t)(colBase + srow + 64) * K + sseg * 8;
    int wvoff = wv * 1024;               // wave-uniform LDS byte offset

    int m0 = (wv >> 1) * 64, n0 = (wv & 1) * 64;
    int fr = lane & 15, fq = lane >> 4;

    f32_4 acc[4][4];
    #pragma unroll
    for (int i = 0; i < 4; i++)
        #pragma unroll
        for (int j = 0; j < 4; j++) acc[i][j] = (f32_4){0.f, 0.f, 0.f, 0.f};

#define STAGE(bufi, koff)                                                  \
    do {                                                                   \
        glld16(aS0 + (koff), (char*)&As[bufi][0] + wvoff);                 \
        glld16(aS1 + (koff), (char*)&As[bufi][0] + 4096 + wvoff);          \
        glld16(bS0 + (koff), (char*)&Bs[bufi][0] + wvoff);                 \
        glld16(bS1 + (koff), (char*)&Bs[bufi][0] + 4096 + wvoff);          \
    } while (0)

    STAGE(0, 0);
    __syncthreads();                     // drains vmcnt -> buf0 ready
    int cur = 0;
    for (int t = 0; t < 8; ++t) {
        if (t < 7) STAGE(cur ^ 1, (t + 1) * BK);   // prefetch next tile
        bf16_8 af[4], bb[4];
        #pragma unroll
        for (int mi = 0; mi < 4; mi++)
            af[mi] = *(const bf16_8*)&As[cur][(m0 + mi * 16 + fr) * BK + fq * 8];
        #pragma unroll
        for (int ni = 0; ni < 4; ni++)
            bb[ni] = *(const bf16_8*)&Bs[cur][(n0 + ni * 16 + fr) * BK + fq * 8];
        #pragma unroll
        for (int mi = 0; mi < 4; mi++)
            #pragma unroll
            for (int ni = 0; ni < 4; ni++)
                acc[mi][ni] = __builtin_amdgcn_mfma_f32_16x16x32_bf16(
                    af[mi], bb[ni], acc[mi][ni], 0, 0, 0);
        __syncthreads();                 // one vmcnt(0)+barrier per K-step
        cur ^= 1;
    }
#undef STAGE

    // ---------------- coalesced epilogue via LDS ----------------
    if (MODE == 0) {
        // bias per acc column (scattered scalar fp32 reads, L2-hot; pre-sigmoid)
        float bvv[4];
        #pragma unroll
        for (int ni = 0; ni < 4; ni++) bvv[ni] = bias[colBase + n0 + ni * 16 + fr];
        bool gateBlk = (colBase >= 256);
        __bf16* outp = gateBlk ? out_gate : out_xin;
        int colOff = colBase - (gateBlk ? 256 : 0);
        __bf16* eB = (__bf16*)SM;                  // [64][136] bf16, 17.4 KB
        #pragma unroll
        for (int c = 0; c < 2; ++c) {
            if ((m0 >> 6) == c) {                  // wave-uniform
                #pragma unroll
                for (int mi = 0; mi < 4; mi++)
                    #pragma unroll
                    for (int ni = 0; ni < 4; ni++)
                        #pragma unroll
                        for (int r = 0; r < 4; r++) {
                            int lr = (m0 & 63) + mi * 16 + fq * 4 + r;
                            float v = acc[mi][ni][r] + bvv[ni];
                            if (gateBlk) v = sigmoidf_(v);
                            eB[lr * 136 + n0 + ni * 16 + fr] = (__bf16)v;
                        }
            }
            __syncthreads();
            #pragma unroll
            for (int i = 0; i < 4; i++) {
                int idx = i * 256 + tid;           // 1024 = 64 rows x 16 u8
                int row = idx >> 4, u8 = idx & 15;
                bf16_8 vv = *(const bf16_8*)&eB[row * 136 + u8 * 8];
                *(bf16_8*)&outp[(size_t)(rowBase + c * 64 + row) * 256
                                + colOff + u8 * 8] = vv;
            }
            __syncthreads();
        }
    } else {
        float* eF = (float*)SM;                    // [32][132] f32, 16.9 KB
        #pragma unroll
        for (int c = 0; c < 4; ++c) {
            #pragma unroll
            for (int mi = 0; mi < 4; mi++) {
                if (((m0 + mi * 16) >> 5) == c) {  // wave-uniform per mi
                    int lr0 = (m0 + mi * 16) & 31;
                    #pragma unroll
                    for (int ni = 0; ni < 4; ni++)
                        #pragma unroll
                        for (int r = 0; r < 4; r++)
                            eF[(lr0 + fq * 4 + r) * 132 + n0 + ni * 16 + fr]
                                = acc[mi][ni][r];
                }
            }
            __syncthreads();
            #pragma unroll
            for (int i = 0; i < 4; i++) {
                int idx = i * 256 + tid;           // 1024 = 32 rows x 32 f4
                int row = idx >> 5, f4 = idx & 31;
                float4 vv = *(const float4*)&eF[row * 132 + f4 * 4];
                size_t gofs = (size_t)(rowBase + c * 32 + row) * 256
                              + colBase + f4 * 4;
                const float4 xv = *(const float4*)&x0[gofs];
                const float4 bv = *(const float4*)&bias[colBase + f4 * 4];
                vv.x += xv.x + bv.x; vv.y += xv.y + bv.y;
                vv.z += xv.z + bv.z; vv.w += xv.w + bv.w;
                *(float4*)&out_f32[gofs] = vv;
            }
            __syncthreads();
        }
    }
}

// ---------------- fused depthwise 3x3 conv + SiLU + row-scan chunk totals ----
static __device__ __forceinline__ void loadcol(const __bf16* __restrict__ xin,
                                               int b, int h, int w, int d,
                                               float c[3]) {
    if (w < 0 || w >= WWW) { c[0] = c[1] = c[2] = 0.f; return; }
    size_t base = ((size_t)b * LL + (size_t)h * WWW + w) * DD + d;
    c[0] = (h > 0)       ? (float)xin[base - (size_t)WWW * DD] : 0.f;
    c[1] = (float)xin[base];
    c[2] = (h + 1 < HHH) ? (float)xin[base + (size_t)WWW * DD] : 0.f;
}

__global__ __launch_bounds__(256) void conv_tot_kernel(const __bf16* __restrict__ xin,
                                                       const float* __restrict__ cw,
                                                       const float* __restrict__ cb,
                                                       const float* __restrict__ a_logit,
                                                       const float* __restrict__ ssm_b,
                                                       __bf16* __restrict__ u,
                                                       float* __restrict__ tot_f,
                                                       float* __restrict__ tot_b) {
    int cx = blockIdx.x, h = blockIdx.y, b = blockIdx.z;
    int d = threadIdx.x;
    int w0 = cx * TCH;
    float k[9];
    #pragma unroll
    for (int i = 0; i < 9; i++) k[i] = cw[i * DD + d];
    float bias = cb[d];
    float a = sigmoidf_(a_logit[d]);
    a = fminf(fmaxf(a, 1e-4f), 1.0f - 1e-4f);
    float bb = ssm_b[d];

    float cl[3], cc[3], cr[3];
    loadcol(xin, b, h, w0 - 1, d, cl);
    loadcol(xin, b, h, w0,     d, cc);
    loadcol(xin, b, h, w0 + 1, d, cr);

    float v[TCH];
    float sf = 0.f;
    size_t outBase = ((size_t)b * LL + (size_t)h * WWW + w0) * DD + d;
    #pragma unroll
    for (int j = 0; j < TCH; j++) {
        float nx[3];
        loadcol(xin, b, h, w0 + j + 2, d, nx);   // prefetch next column
        float acc = bias;
        acc += k[0] * cl[0] + k[1] * cc[0] + k[2] * cr[0];
        acc += k[3] * cl[1] + k[4] * cc[1] + k[5] * cr[1];
        acc += k[6] * cl[2] + k[7] * cc[2] + k[8] * cr[2];
        float uv = acc * sigmoidf_(acc);
        v[j] = uv;
        u[outBase + (size_t)j * DD] = (__bf16)uv;
        sf = a * sf + bb * uv;
        cl[0] = cc[0]; cl[1] = cc[1]; cl[2] = cc[2];
        cc[0] = cr[0]; cc[1] = cr[1]; cc[2] = cr[2];
        cr[0] = nx[0]; cr[1] = nx[1]; cr[2] = nx[2];
    }
    int chunk = h * 3 + cx;                       // row-major chunk id
    tot_f[((size_t)b * NCH + chunk) * DD + d] = sf;
    float sb = 0.f;
    #pragma unroll
    for (int j = TCH - 1; j >= 0; j--) sb = a * sb + bb * v[j];
    tot_b[((size_t)b * NCH + chunk) * DD + d] = sb;
}

// ---------------- scan pass A (col direction only now) ----------------
__global__ __launch_bounds__(256) void scan_totals_col(const __bf16* __restrict__ u,
                                                       const float* __restrict__ a_logit,
                                                       const float* __restrict__ ssm_b,
                                                       float* __restrict__ tot_f,
                                                       float* __restrict__ tot_b) {
    int blk = blockIdx.x;
    int b = blk / NCH, c = blk - b * NCH;
    int d = threadIdx.x;
    float a = sigmoidf_(a_logit[d]);
    a = fminf(fmaxf(a, 1e-4f), 1.0f - 1e-4f);
    float bb = ssm_b[d];
    size_t base = (size_t)b * LL * DD;
    int t0 = c * TCH;
    float v[TCH];
    #pragma unroll
    for (int j = 0; j < TCH; j++)
        v[j] = (float)u[base + (size_t)spidx<1>(t0 + j) * DD + d];
    float s = 0.f;
    #pragma unroll
    for (int j = 0; j < TCH; j++) s = a * s + bb * v[j];
    tot_f[(size_t)blk * DD + d] = s;
    s = 0.f;
    #pragma unroll
    for (int j = TCH - 1; j >= 0; j--) s = a * s + bb * v[j];
    tot_b[(size_t)blk * DD + d] = s;
}

// ---------------- scan pass B: all 4 carry scans in one dispatch -----------
__global__ __launch_bounds__(256) void scan_carries(const float* __restrict__ tot_all,
                                                    const float* __restrict__ a_logit,
                                                    float* __restrict__ car_all) {
    int b = blockIdx.x;
    int var = blockIdx.y;
    int d = threadIdx.x;
    float a = sigmoidf_(a_logit[d]);
    a = fminf(fmaxf(a, 1e-4f), 1.0f - 1e-4f);
    float a2 = a * a, a4 = a2 * a2, a8 = a4 * a4, a16 = a8 * a8;
    float q = a16 * a16;    // a^TCH
    const float* tot = tot_all + (size_t)var * NB * NCH * DD + (size_t)b * NCH * DD + d;
    float* car = car_all + (size_t)var * NB * NCH * DD + (size_t)b * NCH * DD + d;
    float P = 0.f;
    if ((var & 1) == 0) {
        for (int c0 = 0; c0 < NCH; c0 += 8) {
            float t[8];
            #pragma unroll
            for (int j = 0; j < 8; j++) t[j] = tot[(size_t)(c0 + j) * DD];
            #pragma unroll
            for (int j = 0; j < 8; j++) {
                car[(size_t)(c0 + j) * DD] = P;
                P = q * P + t[j];
            }
        }
    } else {
        for (int c0 = NCH - 8; c0 >= 0; c0 -= 8) {
            float t[8];
            #pragma unroll
            for (int j = 0; j < 8; j++) t[j] = tot[(size_t)(c0 + j) * DD];
            #pragma unroll
            for (int j = 7; j >= 0; j--) {
                car[(size_t)(c0 + j) * DD] = P;
                P = q * P + t[j];
            }
        }
    }
}

// ---------------- scan pass C: apply carries, emit 0.25*(yf+yb) ----------------
template<int DIR>
__global__ __launch_bounds__(256) void scan_apply(const __bf16* __restrict__ u,
                                                  const float* __restrict__ a_logit,
                                                  const float* __restrict__ ssm_b,
                                                  const float* __restrict__ ssm_c,
                                                  const float* __restrict__ ssm_d,
                                                  const float* __restrict__ car_f,
                                                  const float* __restrict__ car_b,
                                                  float* __restrict__ y,
                                                  const __bf16* __restrict__ gate,
                                                  __bf16* __restrict__ g) {
    int blk = blockIdx.x;
    int b = blk / NCH, c = blk - b * NCH;
    int d = threadIdx.x;
    float a = sigmoidf_(a_logit[d]);
    a = fminf(fmaxf(a, 1e-4f), 1.0f - 1e-4f);
    float bb = ssm_b[d], cc = ssm_c[d], dd = ssm_d[d];
    size_t base = (size_t)b * LL * DD;
    int t0 = c * TCH;
    float v[TCH];
    #pragma unroll
    for (int j = 0; j < TCH; j++)
        v[j] = (float)u[base + (size_t)spidx<DIR>(t0 + j) * DD + d];
    float yf[TCH];
    float s = car_f[(size_t)blk * DD + d];
    #pragma unroll
    for (int j = 0; j < TCH; j++) {
        s = a * s + bb * v[j];
        yf[j] = cc * s + dd * v[j];
    }
    s = car_b[(size_t)blk * DD + d];
    #pragma unroll
    for (int j = TCH - 1; j >= 0; j--) {
        s = a * s + bb * v[j];
        float val = 0.25f * (yf[j] + cc * s + dd * v[j]);
        size_t idx = base + (size_t)spidx<DIR>(t0 + j) * DD + d;
        if (DIR == 0) {
            y[idx] = val;
        } else {
            float t = y[idx] + val;
            g[idx] = (__bf16)(t * (float)gate[idx]);
        }
    }
}

extern "C" void kernel_launch(void* const* d_in, const int* in_sizes, int n_in,
                              void* d_out, int out_size, void* d_ws, size_t ws_size,
                              hipStream_t stream) {
    const float* x       = (const float*)d_in[0];
    const float* ln_g    = (const float*)d_in[1];
    const float* ln_b    = (const float*)d_in[2];
    const float* w_in    = (const float*)d_in[3];
    const float* b_in    = (const float*)d_in[4];
    const float* conv_w  = (const float*)d_in[5];
    const float* conv_b  = (const float*)d_in[6];
    const float* a_logit = (const float*)d_in[7];
    const float* ssm_b   = (const float*)d_in[8];
    const float* ssm_c   = (const float*)d_in[9];
    const float* ssm_d   = (const float*)d_in[10];
    const float* w_out   = (const float*)d_in[11];
    const float* b_out   = (const float*)d_in[12];
    float* out = (float*)d_out;

    char* ws = (char*)d_ws;
    const size_t SZH = (size_t)NPIX * DD * sizeof(__bf16);    // 37.7 MB
    const size_t TS  = (size_t)NB * NCH * DD * sizeof(float); // 2.36 MB

    __bf16* hB     = (__bf16*)(ws);                  // h, later reused as g
    __bf16* xinB   = (__bf16*)(ws + SZH);            // x_in bf16
    __bf16* uB     = (__bf16*)(ws + 2 * SZH);        // conv output bf16
    __bf16* gateB  = (__bf16*)(ws + 3 * SZH);        // gate bf16
    float*  tot    = (float*)(ws + 4 * SZH);         // [4][NB][NCH][DD]
    float*  car    = (float*)(ws + 4 * SZH + 4 * TS);
    __bf16* w_inT  = (__bf16*)(ws + 4 * SZH + 8 * TS);
    __bf16* w_outT = w_inT + 512 * 256;
    float* y = out;

    wcvt_kernel<<<512, 256, 0, stream>>>(w_in, w_out, w_inT, w_outT);
    ln_kernel<<<NPIX / 4, 256, 0, stream>>>(x, ln_g, ln_b, hB);
    gemm_bf16<0><<<dim3(NPIX / 128, 4), 256, 0, stream>>>(hB, w_inT, b_in,
                                                          xinB, gateB, nullptr, nullptr);
    // fused conv + row totals
    conv_tot_kernel<<<dim3(WWW / TCH, HHH, NB), 256, 0, stream>>>(
        xinB, conv_w, conv_b, a_logit, ssm_b, uB,
        tot + 0 * (size_t)NB * NCH * DD, tot + 1 * (size_t)NB * NCH * DD);
    // col totals
    scan_totals_col<<<NB * NCH, 256, 0, stream>>>(
        uB, a_logit, ssm_b,
        tot + 2 * (size_t)NB * NCH * DD, tot + 3 * (size_t)NB * NCH * DD);
    // all 4 carry scans
    scan_carries<<<dim3(NB, 4), 256, 0, stream>>>(tot, a_logit, car);
    // row apply -> y (fp32, d_out)
    scan_apply<0><<<NB * NCH, 256, 0, stream>>>(
        uB, a_logit, ssm_b, ssm_c, ssm_d,
        car + 0 * (size_t)NB * NCH * DD, car + 1 * (size_t)NB * NCH * DD,
        y, nullptr, nullptr);
    // col apply + gate -> g (bf16, reuses h slot)
    scan_apply<1><<<NB * NCH, 256, 0, stream>>>(
        uB, a_logit, ssm_b, ssm_c, ssm_d,
        car + 2 * (size_t)NB * NCH * DD, car + 3 * (size_t)NB * NCH * DD,
        y, gateB, hB);
    // out = x0 + g @ w_out + b_out
    gemm_bf16<1><<<dim3(NPIX / 128, 2), 256, 0, stream>>>(hB, w_outT, b_out,
                                                          nullptr, nullptr, out, x);
}

// Round 5
// 373.625 us; speedup vs baseline: 1.4714x; 1.0164x over previous
//
#include <hip/hip_runtime.h>
#include <math.h>

#define DD   256
#define HHH  96
#define WWW  96
#define NB   8
#define LL   9216            // HHH*WWW
#define NPIX (NB*LL)         // 73728
#define TCH  32              // scan chunk length
#define NCH  (LL/TCH)        // 288

typedef __bf16 bf16_8 __attribute__((ext_vector_type(8)));
typedef float  f32_4  __attribute__((ext_vector_type(4)));

static __device__ __forceinline__ float sigmoidf_(float x) {
    return 1.0f / (1.0f + expf(-x));
}

// async global->LDS, 16B per lane. Dest must be wave-uniform base (+lane*16 by HW).
typedef const __attribute__((address_space(1))) void gas_void;
typedef __attribute__((address_space(3))) void las_void;
static __device__ __forceinline__ void glld16(const void* g, void* l) {
    __builtin_amdgcn_global_load_lds((gas_void*)g, (las_void*)l, 16, 0, 0);
}

template<int DIR>
static __device__ __forceinline__ int spidx(int t) {
    if (DIR == 0) return t;
    int w = t / HHH;
    int h = t - w * HHH;
    return h * WWW + w;
}

// ---------------- weight transpose + bf16 cast ----------------
__global__ __launch_bounds__(256) void wcvt_kernel(const float* __restrict__ w_in,
                                                   const float* __restrict__ w_out,
                                                   __bf16* __restrict__ w_inT,
                                                   __bf16* __restrict__ w_outT) {
    int i = blockIdx.x * 256 + threadIdx.x;
    int n = i >> 8, k = i & 255;
    w_inT[i] = (__bf16)w_in[k * 512 + n];
    if (i < 256 * 256) w_outT[i] = (__bf16)w_out[k * 256 + n];
}

// ---------------- LayerNorm over channels -> bf16 ----------------
__global__ __launch_bounds__(256) void ln_kernel(const float* __restrict__ x,
                                                 const float* __restrict__ g,
                                                 const float* __restrict__ b,
                                                 __bf16* __restrict__ h) {
    int wv = threadIdx.x >> 6, lane = threadIdx.x & 63;
    int pix = blockIdx.x * 4 + wv;
    const float4 v = *(const float4*)&x[(size_t)pix * DD + lane * 4];
    float s  = v.x + v.y + v.z + v.w;
    float s2 = v.x * v.x + v.y * v.y + v.z * v.z + v.w * v.w;
    #pragma unroll
    for (int o = 32; o > 0; o >>= 1) {
        s  += __shfl_xor(s, o, 64);
        s2 += __shfl_xor(s2, o, 64);
    }
    float mu  = s * (1.0f / 256.0f);
    float var = s2 * (1.0f / 256.0f) - mu * mu;
    float r = rsqrtf(var + 1e-5f);
    float4 gg = *(const float4*)&g[lane * 4];
    float4 bb = *(const float4*)&b[lane * 4];
    union { ushort4 u; __bf16 e[4]; } o4;
    o4.e[0] = (__bf16)((v.x - mu) * r * gg.x + bb.x);
    o4.e[1] = (__bf16)((v.y - mu) * r * gg.y + bb.y);
    o4.e[2] = (__bf16)((v.z - mu) * r * gg.z + bb.z);
    o4.e[3] = (__bf16)((v.w - mu) * r * gg.w + bb.w);
    *(ushort4*)&h[(size_t)pix * DD + lane * 4] = o4.u;
}

// ---------------- bf16 MFMA GEMM (3-ring counted-vmcnt + LDS epilogue) ----
// K-loop: 3-deep LDS ring, prefetch distance 2 K-steps, s_waitcnt vmcnt(4)
// (never drain to 0 mid-loop) + raw s_barrier. Epilogue: R4's coalesced
// LDS round-trip (proven +22us).
// MODE 0 (N=512): cols<256 -> x_in (bf16); cols>=256 -> sigmoid -> gate (bf16)
// MODE 1 (N=256): out_f32 = acc + bias + x0
template<int MODE>
__global__ __launch_bounds__(256) void gemm_bf16(const __bf16* __restrict__ A,
                                                 const __bf16* __restrict__ BT,
                                                 const float* __restrict__ bias,
                                                 __bf16* __restrict__ out_xin,
                                                 __bf16* __restrict__ out_gate,
                                                 float* __restrict__ out_f32,
                                                 const float* __restrict__ x0) {
    const int K = 256;
    const int BK = 32;
    __shared__ __align__(16) char SM[49152];
    auto As = (__bf16 (*)[128 * BK])SM;            // As[0..2], 8KB each
    auto Bs = (__bf16 (*)[128 * BK])(SM + 24576);  // Bs[0..2]
    int tid = threadIdx.x;
    int lane = tid & 63, wv = tid >> 6;
    int rowBase = blockIdx.x * 128;
    int colBase = blockIdx.y * 128;

    // staging: thread covers 16B chunk c=tid; chunk c -> row=c>>2, seg=c&3
    int srow = tid >> 2, sseg = tid & 3;
    const __bf16* aS0 = A  + (size_t)(rowBase + srow) * K + sseg * 8;
    const __bf16* aS1 = A  + (size_t)(rowBase + srow + 64) * K + sseg * 8;
    const __bf16* bS0 = BT + (size_t)(colBase + srow) * K + sseg * 8;
    const __bf16* bS1 = BT + (size_t)(colBase + srow + 64) * K + sseg * 8;
    int wvoff = wv * 1024;               // wave-uniform LDS byte offset

    int m0 = (wv >> 1) * 64, n0 = (wv & 1) * 64;
    int fr = lane & 15, fq = lane >> 4;

    // MODE 0: pin bias loads BEFORE prologue stages so the loop's vmcnt
    // counting sees only glld traffic (stray VMEM is only conservative,
    // but keep it clean).
    float bvv[4];
    if (MODE == 0) {
        #pragma unroll
        for (int ni = 0; ni < 4; ni++) bvv[ni] = bias[colBase + n0 + ni * 16 + fr];
        asm volatile("" : "+v"(bvv[0]), "+v"(bvv[1]), "+v"(bvv[2]), "+v"(bvv[3]));
    }

#define STAGE(bufi, koff)                                                  \
    do {                                                                   \
        glld16(aS0 + (koff), (char*)&As[bufi][0] + wvoff);                 \
        glld16(aS1 + (koff), (char*)&As[bufi][0] + 4096 + wvoff);          \
        glld16(bS0 + (koff), (char*)&Bs[bufi][0] + wvoff);                 \
        glld16(bS1 + (koff), (char*)&Bs[bufi][0] + 4096 + wvoff);          \
    } while (0)

    STAGE(0, 0);
    STAGE(1, BK);

    f32_4 acc[4][4];
    #pragma unroll
    for (int i = 0; i < 4; i++)
        #pragma unroll
        for (int j = 0; j < 4; j++) acc[i][j] = (f32_4){0.f, 0.f, 0.f, 0.f};

    #pragma unroll
    for (int t = 0; t < 8; ++t) {
        // ensure stage t landed; leave newest stage (t+1) in flight
        if (t < 7) { asm volatile("s_waitcnt vmcnt(4)" ::: "memory"); }
        else       { asm volatile("s_waitcnt vmcnt(0)" ::: "memory"); }
        __builtin_amdgcn_sched_barrier(0);
        __builtin_amdgcn_s_barrier();
        __builtin_amdgcn_sched_barrier(0);
        // prefetch stage t+2 into ring slot (t+2)%3; its last readers were
        // iteration t-1, whose LDS reads completed before this barrier.
        if (t + 2 < 8) STAGE((t + 2) % 3, (t + 2) * BK);
        const int cb = t % 3;
        bf16_8 af[4], bb[4];
        #pragma unroll
        for (int mi = 0; mi < 4; mi++)
            af[mi] = *(const bf16_8*)&As[cb][(m0 + mi * 16 + fr) * BK + fq * 8];
        #pragma unroll
        for (int ni = 0; ni < 4; ni++)
            bb[ni] = *(const bf16_8*)&Bs[cb][(n0 + ni * 16 + fr) * BK + fq * 8];
        #pragma unroll
        for (int mi = 0; mi < 4; mi++)
            #pragma unroll
            for (int ni = 0; ni < 4; ni++)
                acc[mi][ni] = __builtin_amdgcn_mfma_f32_16x16x32_bf16(
                    af[mi], bb[ni], acc[mi][ni], 0, 0, 0);
    }
#undef STAGE
    __syncthreads();                     // K-loop fully done; SM reusable

    // ---------------- coalesced epilogue via LDS ----------------
    if (MODE == 0) {
        bool gateBlk = (colBase >= 256);
        __bf16* outp = gateBlk ? out_gate : out_xin;
        int colOff = colBase - (gateBlk ? 256 : 0);
        __bf16* eB = (__bf16*)SM;                  // [64][136] bf16, 17.4 KB
        #pragma unroll
        for (int c = 0; c < 2; ++c) {
            if ((m0 >> 6) == c) {                  // wave-uniform
                #pragma unroll
                for (int mi = 0; mi < 4; mi++)
                    #pragma unroll
                    for (int ni = 0; ni < 4; ni++)
                        #pragma unroll
                        for (int r = 0; r < 4; r++) {
                            int lr = (m0 & 63) + mi * 16 + fq * 4 + r;
                            float v = acc[mi][ni][r] + bvv[ni];
                            if (gateBlk) v = sigmoidf_(v);
                            eB[lr * 136 + n0 + ni * 16 + fr] = (__bf16)v;
                        }
            }
            __syncthreads();
            #pragma unroll
            for (int i = 0; i < 4; i++) {
                int idx = i * 256 + tid;           // 1024 = 64 rows x 16 u8
                int row = idx >> 4, u8 = idx & 15;
                bf16_8 vv = *(const bf16_8*)&eB[row * 136 + u8 * 8];
                *(bf16_8*)&outp[(size_t)(rowBase + c * 64 + row) * 256
                                + colOff + u8 * 8] = vv;
            }
            __syncthreads();
        }
    } else {
        float* eF = (float*)SM;                    // [32][132] f32, 16.9 KB
        #pragma unroll
        for (int c = 0; c < 4; ++c) {
            #pragma unroll
            for (int mi = 0; mi < 4; mi++) {
                if (((m0 + mi * 16) >> 5) == c) {  // wave-uniform per mi
                    int lr0 = (m0 + mi * 16) & 31;
                    #pragma unroll
                    for (int ni = 0; ni < 4; ni++)
                        #pragma unroll
                        for (int r = 0; r < 4; r++)
                            eF[(lr0 + fq * 4 + r) * 132 + n0 + ni * 16 + fr]
                                = acc[mi][ni][r];
                }
            }
            __syncthreads();
            #pragma unroll
            for (int i = 0; i < 4; i++) {
                int idx = i * 256 + tid;           // 1024 = 32 rows x 32 f4
                int row = idx >> 5, f4 = idx & 31;
                float4 vv = *(const float4*)&eF[row * 132 + f4 * 4];
                size_t gofs = (size_t)(rowBase + c * 32 + row) * 256
                              + colBase + f4 * 4;
                const float4 xv = *(const float4*)&x0[gofs];
                const float4 bv = *(const float4*)&bias[colBase + f4 * 4];
                vv.x += xv.x + bv.x; vv.y += xv.y + bv.y;
                vv.z += xv.z + bv.z; vv.w += xv.w + bv.w;
                *(float4*)&out_f32[gofs] = vv;
            }
            __syncthreads();
        }
    }
}

// ---------------- fused depthwise 3x3 conv + SiLU + row-scan chunk totals ----
static __device__ __forceinline__ void loadcol(const __bf16* __restrict__ xin,
                                               int b, int h, int w, int d,
                                               float c[3]) {
    if (w < 0 || w >= WWW) { c[0] = c[1] = c[2] = 0.f; return; }
    size_t base = ((size_t)b * LL + (size_t)h * WWW + w) * DD + d;
    c[0] = (h > 0)       ? (float)xin[base - (size_t)WWW * DD] : 0.f;
    c[1] = (float)xin[base];
    c[2] = (h + 1 < HHH) ? (float)xin[base + (size_t)WWW * DD] : 0.f;
}

__global__ __launch_bounds__(256) void conv_tot_kernel(const __bf16* __restrict__ xin,
                                                       const float* __restrict__ cw,
                                                       const float* __restrict__ cb,
                                                       const float* __restrict__ a_logit,
                                                       const float* __restrict__ ssm_b,
                                                       __bf16* __restrict__ u,
                                                       float* __restrict__ tot_f,
                                                       float* __restrict__ tot_b) {
    int cx = blockIdx.x, h = blockIdx.y, b = blockIdx.z;
    int d = threadIdx.x;
    int w0 = cx * TCH;
    float k[9];
    #pragma unroll
    for (int i = 0; i < 9; i++) k[i] = cw[i * DD + d];
    float bias = cb[d];
    float a = sigmoidf_(a_logit[d]);
    a = fminf(fmaxf(a, 1e-4f), 1.0f - 1e-4f);
    float bb = ssm_b[d];

    float cl[3], cc[3], cr[3];
    loadcol(xin, b, h, w0 - 1, d, cl);
    loadcol(xin, b, h, w0,     d, cc);
    loadcol(xin, b, h, w0 + 1, d, cr);

    float v[TCH];
    float sf = 0.f;
    size_t outBase = ((size_t)b * LL + (size_t)h * WWW + w0) * DD + d;
    #pragma unroll
    for (int j = 0; j < TCH; j++) {
        float nx[3];
        loadcol(xin, b, h, w0 + j + 2, d, nx);   // prefetch next column
        float acc = bias;
        acc += k[0] * cl[0] + k[1] * cc[0] + k[2] * cr[0];
        acc += k[3] * cl[1] + k[4] * cc[1] + k[5] * cr[1];
        acc += k[6] * cl[2] + k[7] * cc[2] + k[8] * cr[2];
        float uv = acc * sigmoidf_(acc);
        v[j] = uv;
        u[outBase + (size_t)j * DD] = (__bf16)uv;
        sf = a * sf + bb * uv;
        cl[0] = cc[0]; cl[1] = cc[1]; cl[2] = cc[2];
        cc[0] = cr[0]; cc[1] = cr[1]; cc[2] = cr[2];
        cr[0] = nx[0]; cr[1] = nx[1]; cr[2] = nx[2];
    }
    int chunk = h * 3 + cx;                       // row-major chunk id
    tot_f[((size_t)b * NCH + chunk) * DD + d] = sf;
    float sb = 0.f;
    #pragma unroll
    for (int j = TCH - 1; j >= 0; j--) sb = a * sb + bb * v[j];
    tot_b[((size_t)b * NCH + chunk) * DD + d] = sb;
}

// ---------------- scan pass A (col direction only now) ----------------
__global__ __launch_bounds__(256) void scan_totals_col(const __bf16* __restrict__ u,
                                                       const float* __restrict__ a_logit,
                                                       const float* __restrict__ ssm_b,
                                                       float* __restrict__ tot_f,
                                                       float* __restrict__ tot_b) {
    int blk = blockIdx.x;
    int b = blk / NCH, c = blk - b * NCH;
    int d = threadIdx.x;
    float a = sigmoidf_(a_logit[d]);
    a = fminf(fmaxf(a, 1e-4f), 1.0f - 1e-4f);
    float bb = ssm_b[d];
    size_t base = (size_t)b * LL * DD;
    int t0 = c * TCH;
    float v[TCH];
    #pragma unroll
    for (int j = 0; j < TCH; j++)
        v[j] = (float)u[base + (size_t)spidx<1>(t0 + j) * DD + d];
    float s = 0.f;
    #pragma unroll
    for (int j = 0; j < TCH; j++) s = a * s + bb * v[j];
    tot_f[(size_t)blk * DD + d] = s;
    s = 0.f;
    #pragma unroll
    for (int j = TCH - 1; j >= 0; j--) s = a * s + bb * v[j];
    tot_b[(size_t)blk * DD + d] = s;
}

// ---------------- scan pass B: all 4 carry scans in one dispatch -----------
__global__ __launch_bounds__(256) void scan_carries(const float* __restrict__ tot_all,
                                                    const float* __restrict__ a_logit,
                                                    float* __restrict__ car_all) {
    int b = blockIdx.x;
    int var = blockIdx.y;
    int d = threadIdx.x;
    float a = sigmoidf_(a_logit[d]);
    a = fminf(fmaxf(a, 1e-4f), 1.0f - 1e-4f);
    float a2 = a * a, a4 = a2 * a2, a8 = a4 * a4, a16 = a8 * a8;
    float q = a16 * a16;    // a^TCH
    const float* tot = tot_all + (size_t)var * NB * NCH * DD + (size_t)b * NCH * DD + d;
    float* car = car_all + (size_t)var * NB * NCH * DD + (size_t)b * NCH * DD + d;
    float P = 0.f;
    if ((var & 1) == 0) {
        for (int c0 = 0; c0 < NCH; c0 += 8) {
            float t[8];
            #pragma unroll
            for (int j = 0; j < 8; j++) t[j] = tot[(size_t)(c0 + j) * DD];
            #pragma unroll
            for (int j = 0; j < 8; j++) {
                car[(size_t)(c0 + j) * DD] = P;
                P = q * P + t[j];
            }
        }
    } else {
        for (int c0 = NCH - 8; c0 >= 0; c0 -= 8) {
            float t[8];
            #pragma unroll
            for (int j = 0; j < 8; j++) t[j] = tot[(size_t)(c0 + j) * DD];
            #pragma unroll
            for (int j = 7; j >= 0; j--) {
                car[(size_t)(c0 + j) * DD] = P;
                P = q * P + t[j];
            }
        }
    }
}

// ---------------- scan pass C: apply carries, emit 0.25*(yf+yb) ----------------
template<int DIR>
__global__ __launch_bounds__(256) void scan_apply(const __bf16* __restrict__ u,
                                                  const float* __restrict__ a_logit,
                                                  const float* __restrict__ ssm_b,
                                                  const float* __restrict__ ssm_c,
                                                  const float* __restrict__ ssm_d,
                                                  const float* __restrict__ car_f,
                                                  const float* __restrict__ car_b,
                                                  float* __restrict__ y,
                                                  const __bf16* __restrict__ gate,
                                                  __bf16* __restrict__ g) {
    int blk = blockIdx.x;
    int b = blk / NCH, c = blk - b * NCH;
    int d = threadIdx.x;
    float a = sigmoidf_(a_logit[d]);
    a = fminf(fmaxf(a, 1e-4f), 1.0f - 1e-4f);
    float bb = ssm_b[d], cc = ssm_c[d], dd = ssm_d[d];
    size_t base = (size_t)b * LL * DD;
    int t0 = c * TCH;
    float v[TCH];
    #pragma unroll
    for (int j = 0; j < TCH; j++)
        v[j] = (float)u[base + (size_t)spidx<DIR>(t0 + j) * DD + d];
    float yf[TCH];
    float s = car_f[(size_t)blk * DD + d];
    #pragma unroll
    for (int j = 0; j < TCH; j++) {
        s = a * s + bb * v[j];
        yf[j] = cc * s + dd * v[j];
    }
    s = car_b[(size_t)blk * DD + d];
    #pragma unroll
    for (int j = TCH - 1; j >= 0; j--) {
        s = a * s + bb * v[j];
        float val = 0.25f * (yf[j] + cc * s + dd * v[j]);
        size_t idx = base + (size_t)spidx<DIR>(t0 + j) * DD + d;
        if (DIR == 0) {
            y[idx] = val;
        } else {
            float t = y[idx] + val;
            g[idx] = (__bf16)(t * (float)gate[idx]);
        }
    }
}

extern "C" void kernel_launch(void* const* d_in, const int* in_sizes, int n_in,
                              void* d_out, int out_size, void* d_ws, size_t ws_size,
                              hipStream_t stream) {
    const float* x       = (const float*)d_in[0];
    const float* ln_g    = (const float*)d_in[1];
    const float* ln_b    = (const float*)d_in[2];
    const float* w_in    = (const float*)d_in[3];
    const float* b_in    = (const float*)d_in[4];
    const float* conv_w  = (const float*)d_in[5];
    const float* conv_b  = (const float*)d_in[6];
    const float* a_logit = (const float*)d_in[7];
    const float* ssm_b   = (const float*)d_in[8];
    const float* ssm_c   = (const float*)d_in[9];
    const float* ssm_d   = (const float*)d_in[10];
    const float* w_out   = (const float*)d_in[11];
    const float* b_out   = (const float*)d_in[12];
    float* out = (float*)d_out;

    char* ws = (char*)d_ws;
    const size_t SZH = (size_t)NPIX * DD * sizeof(__bf16);    // 37.7 MB
    const size_t TS  = (size_t)NB * NCH * DD * sizeof(float); // 2.36 MB

    __bf16* hB     = (__bf16*)(ws);                  // h, later reused as g
    __bf16* xinB   = (__bf16*)(ws + SZH);            // x_in bf16
    __bf16* uB     = (__bf16*)(ws + 2 * SZH);        // conv output bf16
    __bf16* gateB  = (__bf16*)(ws + 3 * SZH);        // gate bf16
    float*  tot    = (float*)(ws + 4 * SZH);         // [4][NB][NCH][DD]
    float*  car    = (float*)(ws + 4 * SZH + 4 * TS);
    __bf16* w_inT  = (__bf16*)(ws + 4 * SZH + 8 * TS);
    __bf16* w_outT = w_inT + 512 * 256;
    float* y = out;

    wcvt_kernel<<<512, 256, 0, stream>>>(w_in, w_out, w_inT, w_outT);
    ln_kernel<<<NPIX / 4, 256, 0, stream>>>(x, ln_g, ln_b, hB);
    gemm_bf16<0><<<dim3(NPIX / 128, 4), 256, 0, stream>>>(hB, w_inT, b_in,
                                                          xinB, gateB, nullptr, nullptr);
    // fused conv + row totals
    conv_tot_kernel<<<dim3(WWW / TCH, HHH, NB), 256, 0, stream>>>(
        xinB, conv_w, conv_b, a_logit, ssm_b, uB,
        tot + 0 * (size_t)NB * NCH * DD, tot + 1 * (size_t)NB * NCH * DD);
    // col totals
    scan_totals_col<<<NB * NCH, 256, 0, stream>>>(
        uB, a_logit, ssm_b,
        tot + 2 * (size_t)NB * NCH * DD, tot + 3 * (size_t)NB * NCH * DD);
    // all 4 carry scans
    scan_carries<<<dim3(NB, 4), 256, 0, stream>>>(tot, a_logit, car);
    // row apply -> y (fp32, d_out)
    scan_apply<0><<<NB * NCH, 256, 0, stream>>>(
        uB, a_logit, ssm_b, ssm_c, ssm_d,
        car + 0 * (size_t)NB * NCH * DD, car + 1 * (size_t)NB * NCH * DD,
        y, nullptr, nullptr);
    // col apply + gate -> g (bf16, reuses h slot)
    scan_apply<1><<<NB * NCH, 256, 0, stream>>>(
        uB, a_logit, ssm_b, ssm_c, ssm_d,
        car + 2 * (size_t)NB * NCH * DD, car + 3 * (size_t)NB * NCH * DD,
        y, gateB, hB);
    // out = x0 + g @ w_out + b_out
    gemm_bf16<1><<<dim3(NPIX / 128, 2), 256, 0, stream>>>(hB, w_outT, b_out,
                                                          nullptr, nullptr, out, x);
}